// Round 11
// baseline (1476.993 us; speedup 1.0000x reference)
//
#include <hip/hip_runtime.h>
#include <hip/hip_bf16.h>

typedef unsigned short u16;
typedef unsigned int u32;
typedef short bf16x8 __attribute__((ext_vector_type(8)));
typedef float f32x4 __attribute__((ext_vector_type(4)));

#define BAR() asm volatile("s_barrier" ::: "memory")
#define WAITV8() asm volatile("s_waitcnt vmcnt(8)" ::: "memory")
#define WAITV4() asm volatile("s_waitcnt vmcnt(4)" ::: "memory")
#define WAITV0() asm volatile("s_waitcnt vmcnt(0)" ::: "memory")
#define WAITL() asm volatile("s_waitcnt lgkmcnt(0)" ::: "memory")

// ---------- helpers ----------
__device__ __forceinline__ unsigned pk2(float lo, float hi) {
    unsigned a = (unsigned)__builtin_bit_cast(u16, __float2bfloat16(lo));
    unsigned b = (unsigned)__builtin_bit_cast(u16, __float2bfloat16(hi));
    return a | (b << 16);
}
__device__ __forceinline__ u16 f2bf(float v) {
    return __builtin_bit_cast(u16, __float2bfloat16(v));
}
__device__ __forceinline__ void gl_lds16(const u16* g, u16* l) {
    __builtin_amdgcn_global_load_lds(
        (const __attribute__((address_space(1))) u32*)g,
        (__attribute__((address_space(3))) u32*)l, 16, 0, 0);
}

// ---------- f32 -> bf16 weight convert ----------
__global__ void cvtbf(const float4* __restrict__ s, uint2* __restrict__ d, int n4) {
    int i = blockIdx.x * blockDim.x + threadIdx.x;
    int stride = gridDim.x * blockDim.x;
    for (; i < n4; i += stride) {
        float4 f = s[i];
        uint2 o;
        o.x = pk2(f.x, f.y);
        o.y = pk2(f.z, f.w);
        d[i] = o;
    }
}

// ---------- build x = [u_t | emb[s_i]] as bf16 [65536][1536] ----------
__global__ __launch_bounds__(256) void xbuild(const float* __restrict__ u_t,
                                              const float* __restrict__ emb,
                                              const int* __restrict__ s_i,
                                              u16* __restrict__ xb) {
    const long u = (long)blockIdx.x * blockDim.x + threadIdx.x;
    const int row = (int)(u / 192);
    const int c8 = (int)(u % 192);
    const float* src = (c8 < 96) ? (u_t + (long)row * 768 + c8 * 8)
                                 : (emb + (long)s_i[row] * 768 + (c8 - 96) * 8);
    float4 f0 = ((const float4*)src)[0];
    float4 f1 = ((const float4*)src)[1];
    uint4 o;
    o.x = pk2(f0.x, f0.y);
    o.y = pk2(f0.z, f0.w);
    o.z = pk2(f1.x, f1.y);
    o.w = pk2(f1.z, f1.w);
    *(uint4*)(xb + u * 8) = o;
}

// ---------- 256x256 8-phase GEMM, 3-half-tile-deep prefetch ----------------
// A [M][LDK] bf16, B [TN*256][LDK] bf16. EPI 0: tanh-GELU->bf16, EPI 1: bias->f32.
// vs R8: tile t+1's half0 (A+B) issued at P0, half1 at P1 -> issue->wait
// distance 3-4 phases (was 2). Waits: end-P1 vmcnt(8) drains h1(t);
// end-P3 vmcnt(4) drains h0(t+1); last tile drains to 0 (R3 lesson).
// LDS: lds[buf][A/B][ks][256*32 u16], chunk swizzle c' = c ^ ((row>>1)&3),
// applied on global source + ds_read side (linear gl_lds dest, rule 21).
template <int LDK, int NT, int TN, int EPI>
__global__ __launch_bounds__(512, 2) void gemm256(
    const u16* __restrict__ Ag, const u16* __restrict__ Bg,
    const float* __restrict__ bias, u16* __restrict__ outb,
    float* __restrict__ outf) {
    __shared__ __align__(16) u16 lds[65536];  // 128 KiB

    const int tid = threadIdx.x;
    const int lane = tid & 63;
    const int wv = tid >> 6;
    const int wm = wv >> 2;  // 0..1
    const int wn = wv & 3;   // 0..3

    const int cpx = (int)gridDim.x >> 3;  // grid % 8 == 0
    const int tile = ((int)blockIdx.x & 7) * cpx + ((int)blockIdx.x >> 3);
    const int tm = tile / TN, tn = tile % TN;
    const long rowBase = (long)tm * 256;
    const long colBase = (long)tn * 256;

    // --- staging map: thread -> (row = tid>>2 [+128], swizzled 16B chunk) ---
    const int srow = tid >> 2;
    const int gch = (tid & 3) ^ ((tid >> 3) & 3);
    const u16* pA = Ag + (rowBase + srow) * (long)LDK + gch * 8;
    const u16* pB = Bg + (colBase + srow) * (long)LDK + gch * 8;
    const int dstBase = wv * 512;  // u16 units within 8KB sub-block

    auto stageA = [&](int kt, int ks, int b) {
        const u16* s = pA + kt * 64 + ks * 32;
        u16* d = lds + b * 32768 + ks * 8192 + dstBase;
        gl_lds16(s, d);
        gl_lds16(s + (long)128 * LDK, d + 4096);
    };
    auto stageB = [&](int kt, int ks, int b) {
        const u16* s = pB + kt * 64 + ks * 32;
        u16* d = lds + b * 32768 + 16384 + ks * 8192 + dstBase;
        gl_lds16(s, d);
        gl_lds16(s + (long)128 * LDK, d + 4096);
    };

    // --- fragment read offsets (u16 units, relative to 8KB ks-region) ---
    const int l15 = lane & 15, lc = lane >> 4;
    int offA[8], offB[4];
#pragma unroll
    for (int i = 0; i < 8; ++i) {
        int r = wm * 128 + i * 16 + l15;
        offA[i] = r * 32 + ((lc ^ ((r >> 1) & 3)) << 3);
    }
#pragma unroll
    for (int n = 0; n < 4; ++n) {
        int r = wn * 64 + n * 16 + l15;
        offB[n] = r * 32 + ((lc ^ ((r >> 1) & 3)) << 3);
    }

    f32x4 acc[8][4];
    const f32x4 zero = {0.f, 0.f, 0.f, 0.f};
#pragma unroll
    for (int m = 0; m < 8; ++m)
#pragma unroll
        for (int n = 0; n < 4; ++n) acc[m][n] = zero;

    // --- prologue: stage tile 0 fully; drain h0 pair (h1 stays in flight) ---
    stageA(0, 0, 0);
    stageB(0, 0, 0);
    stageA(0, 1, 0);
    stageB(0, 1, 0);
    WAITV4();
    BAR();

    bf16x8 bA[4], bB[4];
    for (int kt = 0; kt < NT; ++kt) {
        const int b = kt & 1;
        const u16* rA0 = lds + b * 32768;
        const u16* rB0 = rA0 + 16384;
        const u16* rA1 = rA0 + 8192;
        const u16* rB1 = rB0 + 8192;
        const bool pf = (kt + 1 < NT);

        // ---- P0: ks0, m-half0 (+ issue t+1 half0: A and B) ----
#pragma unroll
        for (int n = 0; n < 4; ++n) bB[n] = *(const bf16x8*)(rB0 + offB[n]);
#pragma unroll
        for (int m = 0; m < 4; ++m) bA[m] = *(const bf16x8*)(rA0 + offA[m]);
        if (pf) { stageA(kt + 1, 0, b ^ 1); stageB(kt + 1, 0, b ^ 1); }
        BAR();
        WAITL();
        __builtin_amdgcn_s_setprio(1);
#pragma unroll
        for (int m = 0; m < 4; ++m)
#pragma unroll
            for (int n = 0; n < 4; ++n)
                acc[m][n] = __builtin_amdgcn_mfma_f32_16x16x32_bf16(bA[m], bB[n], acc[m][n], 0, 0, 0);
        __builtin_amdgcn_s_setprio(0);
        BAR();

        // ---- P1: ks0, m-half1 (+ issue t+1 half1: A and B) ----
#pragma unroll
        for (int m = 0; m < 4; ++m) bA[m] = *(const bf16x8*)(rA0 + offA[4 + m]);
        if (pf) { stageA(kt + 1, 1, b ^ 1); stageB(kt + 1, 1, b ^ 1); }
        BAR();
        WAITL();
        __builtin_amdgcn_s_setprio(1);
#pragma unroll
        for (int m = 0; m < 4; ++m)
#pragma unroll
            for (int n = 0; n < 4; ++n)
                acc[4 + m][n] = __builtin_amdgcn_mfma_f32_16x16x32_bf16(bA[m], bB[n], acc[4 + m][n], 0, 0, 0);
        __builtin_amdgcn_s_setprio(0);
        // need h1(t) [issued P1 of t-1, 4 phases ago]. Outstanding if pf:
        // h1(t) 4 + h0(t+1) 4 + h1(t+1) 4 = 12 -> vmcnt(8). Last tile: only
        // h1(t) outstanding -> drain fully (R3 lesson).
        if (pf) { WAITV8(); } else { WAITV0(); }
        BAR();

        // ---- P2: ks1, m-half0 ----
#pragma unroll
        for (int n = 0; n < 4; ++n) bB[n] = *(const bf16x8*)(rB1 + offB[n]);
#pragma unroll
        for (int m = 0; m < 4; ++m) bA[m] = *(const bf16x8*)(rA1 + offA[m]);
        BAR();
        WAITL();
        __builtin_amdgcn_s_setprio(1);
#pragma unroll
        for (int m = 0; m < 4; ++m)
#pragma unroll
            for (int n = 0; n < 4; ++n)
                acc[m][n] = __builtin_amdgcn_mfma_f32_16x16x32_bf16(bA[m], bB[n], acc[m][n], 0, 0, 0);
        __builtin_amdgcn_s_setprio(0);
        BAR();

        // ---- P3: ks1, m-half1 ----
#pragma unroll
        for (int m = 0; m < 4; ++m) bA[m] = *(const bf16x8*)(rA1 + offA[4 + m]);
        BAR();
        WAITL();
        __builtin_amdgcn_s_setprio(1);
#pragma unroll
        for (int m = 0; m < 4; ++m)
#pragma unroll
            for (int n = 0; n < 4; ++n)
                acc[4 + m][n] = __builtin_amdgcn_mfma_f32_16x16x32_bf16(bA[m], bB[n], acc[4 + m][n], 0, 0, 0);
        __builtin_amdgcn_s_setprio(0);
        // need h0(t+1) [issued P0 of t, 3 phases ago]. Outstanding if pf:
        // h0(t+1) 4 + h1(t+1) 4 = 8 -> vmcnt(4). Last tile: nothing.
        if (pf) { WAITV4(); } else { WAITV0(); }
        BAR();
    }

    // ---- epilogue ----
    const int N = TN * 256;
#pragma unroll
    for (int n = 0; n < 4; ++n) {
        long gc = colBase + wn * 64 + n * 16 + l15;
        float bv = bias[gc];
#pragma unroll
        for (int i = 0; i < 8; ++i) {
            long gr = rowBase + wm * 128 + i * 16 + (lc << 2);
#pragma unroll
            for (int j = 0; j < 4; ++j) {
                float v = acc[i][n][j] + bv;
                if constexpr (EPI == 0) {
                    // gelu(v) = v * sigmoid(2u), u = 0.79788456(v + 0.044715 v^3)
                    float w = v * v;
                    float z = v * fmaf(w, -0.0713548162f, -1.5957691216f);  // -2u
                    v = __fdividef(v, 1.0f + __expf(z));
                    outb[(gr + j) * N + gc] = f2bf(v);
                } else {
                    outf[(gr + j) * N + gc] = v;
                }
            }
        }
    }
}

// ---------- LayerNorm (in place, f32) + scatter-add into updated ----------
__global__ __launch_bounds__(256) void ln_scatter(float* __restrict__ y,
                                                  const float* __restrict__ gamma,
                                                  const float* __restrict__ beta,
                                                  const int* __restrict__ s_i,
                                                  float* __restrict__ upd) {
    const int lane = threadIdx.x & 63;
    const long row = (long)blockIdx.x * 4 + (threadIdx.x >> 6);
    const long base = row * 768;
    float v[12];
#pragma unroll
    for (int i = 0; i < 12; ++i) v[i] = y[base + i * 64 + lane];
    float s = 0.f, q = 0.f;
#pragma unroll
    for (int i = 0; i < 12; ++i) { s += v[i]; q += v[i] * v[i]; }
#pragma unroll
    for (int off = 32; off > 0; off >>= 1) {
        s += __shfl_xor(s, off, 64);
        q += __shfl_xor(q, off, 64);
    }
    const float mu = s * (1.f / 768.f);
    const float var = q * (1.f / 768.f) - mu * mu;
    const float inv = rsqrtf(var + 1e-5f);
    const long si = s_i[row];
#pragma unroll
    for (int i = 0; i < 12; ++i) {
        int c = i * 64 + lane;
        float r = (v[i] - mu) * inv * gamma[c] + beta[c];
        y[base + c] = r;
        atomicAdd(&upd[si * 768 + c], r);
    }
}

// ---------- plain float4 copy ----------
__global__ void copy4(const float4* __restrict__ s, float4* __restrict__ d, long n) {
    long i = (long)blockIdx.x * blockDim.x + threadIdx.x;
    long stride = (long)gridDim.x * blockDim.x;
    for (; i < n; i += stride) d[i] = s[i];
}

extern "C" void kernel_launch(void* const* d_in, const int* in_sizes, int n_in,
                              void* d_out, int out_size, void* d_ws, size_t ws_size,
                              hipStream_t stream) {
    const float* u_t = (const float*)d_in[0];
    const int* s_i = (const int*)d_in[1];
    const float* emb = (const float*)d_in[2];
    const float* W1 = (const float*)d_in[3];
    const float* b1 = (const float*)d_in[4];
    const float* W2 = (const float*)d_in[5];
    const float* b2 = (const float*)d_in[6];
    const float* gamma = (const float*)d_in[7];
    const float* beta = (const float*)d_in[8];

    float* out = (float*)d_out;
    float* newh = out;             // [65536,768] f32 (y, then LN in place) - NOT in upd
    float* upd = out + 50331648L;  // [262144,768] f32 (scratch first, final last)

    // scratch inside upd (all dead before copy4 runs):
    u16* base = (u16*)upd;
    u16* xb = base;                    // [65536,1536] bf16
    u16* w1b = base + 100663296L;      // [2048,1536] bf16
    u16* hbuf = base + 103809024L;     // [65536,2048] bf16
    u16* w2b = base + 238026752L;      // [768,2048] bf16

    cvtbf<<<1024, 256, 0, stream>>>((const float4*)W1, (uint2*)w1b, 786432);
    cvtbf<<<1024, 256, 0, stream>>>((const float4*)W2, (uint2*)w2b, 393216);
    xbuild<<<49152, 256, 0, stream>>>(u_t, emb, s_i, xb);
    // GEMM1: M=65536, N=2048, K=1536 -> 2048 tiles (tanh-GELU, bf16 out)
    gemm256<1536, 24, 8, 0><<<2048, 512, 0, stream>>>(xb, w1b, b1, hbuf, nullptr);
    // GEMM2: M=65536, N=768, K=2048 -> 768 tiles (bias, f32 into newh)
    gemm256<2048, 32, 3, 1><<<768, 512, 0, stream>>>(hbuf, w2b, b2, nullptr, newh);
    copy4<<<2048, 256, 0, stream>>>((const float4*)emb, (float4*)upd, 50331648L);
    ln_scatter<<<16384, 256, 0, stream>>>(newh, gamma, beta, s_i, upd);
}

// Round 12
// 1459.639 us; speedup vs baseline: 1.0119x; 1.0119x over previous
//
#include <hip/hip_runtime.h>
#include <hip/hip_bf16.h>

typedef unsigned short u16;
typedef unsigned int u32;
typedef short bf16x8 __attribute__((ext_vector_type(8)));
typedef float f32x4 __attribute__((ext_vector_type(4)));

#define BAR() asm volatile("s_barrier" ::: "memory")
#define WAITV8() asm volatile("s_waitcnt vmcnt(8)" ::: "memory")
#define WAITV0() asm volatile("s_waitcnt vmcnt(0)" ::: "memory")

// ---------- helpers ----------
__device__ __forceinline__ unsigned pk2(float lo, float hi) {
    unsigned a = (unsigned)__builtin_bit_cast(u16, __float2bfloat16(lo));
    unsigned b = (unsigned)__builtin_bit_cast(u16, __float2bfloat16(hi));
    return a | (b << 16);
}
__device__ __forceinline__ u16 f2bf(float v) {
    return __builtin_bit_cast(u16, __float2bfloat16(v));
}
__device__ __forceinline__ void gl_lds16(const u16* g, u16* l) {
    __builtin_amdgcn_global_load_lds(
        (const __attribute__((address_space(1))) u32*)g,
        (__attribute__((address_space(3))) u32*)l, 16, 0, 0);
}

// ---------- f32 -> bf16 weight convert ----------
__global__ void cvtbf(const float4* __restrict__ s, uint2* __restrict__ d, int n4) {
    int i = blockIdx.x * blockDim.x + threadIdx.x;
    int stride = gridDim.x * blockDim.x;
    for (; i < n4; i += stride) {
        float4 f = s[i];
        uint2 o;
        o.x = pk2(f.x, f.y);
        o.y = pk2(f.z, f.w);
        d[i] = o;
    }
}

// ---------- build x = [u_t | emb[s_i]] as bf16 [65536][1536] ----------
__global__ __launch_bounds__(256) void xbuild(const float* __restrict__ u_t,
                                              const float* __restrict__ emb,
                                              const int* __restrict__ s_i,
                                              u16* __restrict__ xb) {
    const long u = (long)blockIdx.x * blockDim.x + threadIdx.x;
    const int row = (int)(u / 192);
    const int c8 = (int)(u % 192);
    const float* src = (c8 < 96) ? (u_t + (long)row * 768 + c8 * 8)
                                 : (emb + (long)s_i[row] * 768 + (c8 - 96) * 8);
    float4 f0 = ((const float4*)src)[0];
    float4 f1 = ((const float4*)src)[1];
    uint4 o;
    o.x = pk2(f0.x, f0.y);
    o.y = pk2(f0.z, f0.w);
    o.z = pk2(f1.x, f1.y);
    o.w = pk2(f1.z, f1.w);
    *(uint4*)(xb + u * 8) = o;
}

// ---------- 256x256 GEMM, 2-barrier/K-tile, counted-vmcnt dbuf -------------
// A [M][LDK] bf16, B [TN*256][LDK] bf16. EPI 0: tanh-GELU->bf16, EPI 1: bias->f32.
// Per K-tile: {issue 8 gl_lds for t+1 -> buf^1} -> vmcnt(8) [drains t's 8,
// issued one full K-tile ago] -> BAR -> 24 ds_read + 64 MFMA (compiler
// schedules fine lgkmcnt interleave) -> BAR. Last tile: vmcnt(0) (R3 lesson).
// LDS: lds[buf][A/B][ks][256*32 u16], chunk swizzle c' = c ^ ((row>>1)&3),
// on global source + ds_read side (linear gl_lds dest, rule 21).
template <int LDK, int NT, int TN, int EPI>
__global__ __launch_bounds__(512, 2) void gemm256(
    const u16* __restrict__ Ag, const u16* __restrict__ Bg,
    const float* __restrict__ bias, u16* __restrict__ outb,
    float* __restrict__ outf) {
    __shared__ __align__(16) u16 lds[65536];  // 128 KiB

    const int tid = threadIdx.x;
    const int lane = tid & 63;
    const int wv = tid >> 6;
    const int wm = wv >> 2;  // 0..1
    const int wn = wv & 3;   // 0..3

    const int cpx = (int)gridDim.x >> 3;  // grid % 8 == 0
    const int tile = ((int)blockIdx.x & 7) * cpx + ((int)blockIdx.x >> 3);
    const int tm = tile / TN, tn = tile % TN;
    const long rowBase = (long)tm * 256;
    const long colBase = (long)tn * 256;

    // --- staging map: thread -> (row = tid>>2 [+128], swizzled 16B chunk) ---
    const int srow = tid >> 2;
    const int gch = (tid & 3) ^ ((tid >> 3) & 3);
    const u16* pA = Ag + (rowBase + srow) * (long)LDK + gch * 8;
    const u16* pB = Bg + (colBase + srow) * (long)LDK + gch * 8;
    const int dstBase = wv * 512;  // u16 units within 8KB sub-block

    auto stageA = [&](int kt, int ks, int b) {
        const u16* s = pA + kt * 64 + ks * 32;
        u16* d = lds + b * 32768 + ks * 8192 + dstBase;
        gl_lds16(s, d);
        gl_lds16(s + (long)128 * LDK, d + 4096);
    };
    auto stageB = [&](int kt, int ks, int b) {
        const u16* s = pB + kt * 64 + ks * 32;
        u16* d = lds + b * 32768 + 16384 + ks * 8192 + dstBase;
        gl_lds16(s, d);
        gl_lds16(s + (long)128 * LDK, d + 4096);
    };

    // --- fragment read offsets (u16 units, relative to 8KB ks-region) ---
    const int l15 = lane & 15, lc = lane >> 4;
    int offA[8], offB[4];
#pragma unroll
    for (int i = 0; i < 8; ++i) {
        int r = wm * 128 + i * 16 + l15;
        offA[i] = r * 32 + ((lc ^ ((r >> 1) & 3)) << 3);
    }
#pragma unroll
    for (int n = 0; n < 4; ++n) {
        int r = wn * 64 + n * 16 + l15;
        offB[n] = r * 32 + ((lc ^ ((r >> 1) & 3)) << 3);
    }

    f32x4 acc[8][4];
    const f32x4 zero = {0.f, 0.f, 0.f, 0.f};
#pragma unroll
    for (int m = 0; m < 8; ++m)
#pragma unroll
        for (int n = 0; n < 4; ++n) acc[m][n] = zero;

    // --- prologue: stage tile 0 (8 loads into buf 0); no wait yet ---
    stageA(0, 0, 0);
    stageB(0, 0, 0);
    stageA(0, 1, 0);
    stageB(0, 1, 0);

    for (int kt = 0; kt < NT; ++kt) {
        const int b = kt & 1;
        const bool pf = (kt + 1 < NT);

        // issue next tile's full stage into buf^1 (8 loads)
        if (pf) {
            stageA(kt + 1, 0, b ^ 1);
            stageB(kt + 1, 0, b ^ 1);
            stageA(kt + 1, 1, b ^ 1);
            stageB(kt + 1, 1, b ^ 1);
        }
        // drain tile t's 8 loads (oldest); t+1's 8 stay in flight.
        if (pf) { WAITV8(); } else { WAITV0(); }
        BAR();  // all waves: buf b fully staged

        // compute full K-tile; compiler interleaves ds_read/MFMA with
        // fine-grained lgkmcnt (m97 evidence)
#pragma unroll
        for (int kk = 0; kk < 2; ++kk) {
            const u16* rA = lds + b * 32768 + kk * 8192;
            const u16* rB = lds + b * 32768 + 16384 + kk * 8192;
            bf16x8 xA[8], xB[4];
#pragma unroll
            for (int n = 0; n < 4; ++n) xB[n] = *(const bf16x8*)(rB + offB[n]);
#pragma unroll
            for (int m = 0; m < 8; ++m) xA[m] = *(const bf16x8*)(rA + offA[m]);
#pragma unroll
            for (int m = 0; m < 8; ++m)
#pragma unroll
                for (int n = 0; n < 4; ++n)
                    acc[m][n] = __builtin_amdgcn_mfma_f32_16x16x32_bf16(xA[m], xB[n], acc[m][n], 0, 0, 0);
        }
        BAR();  // all waves done reading buf b (reused for staging at t+2)
    }

    // ---- epilogue ----
    const int N = TN * 256;
#pragma unroll
    for (int n = 0; n < 4; ++n) {
        long gc = colBase + wn * 64 + n * 16 + l15;
        float bv = bias[gc];
#pragma unroll
        for (int i = 0; i < 8; ++i) {
            long gr = rowBase + wm * 128 + i * 16 + (lc << 2);
#pragma unroll
            for (int j = 0; j < 4; ++j) {
                float v = acc[i][n][j] + bv;
                if constexpr (EPI == 0) {
                    // gelu(v) = v * sigmoid(2u), u = 0.79788456(v + 0.044715 v^3)
                    float w = v * v;
                    float z = v * fmaf(w, -0.0713548162f, -1.5957691216f);  // -2u
                    v = __fdividef(v, 1.0f + __expf(z));
                    outb[(gr + j) * N + gc] = f2bf(v);
                } else {
                    outf[(gr + j) * N + gc] = v;
                }
            }
        }
    }
}

// ---------- LayerNorm (in place, f32) + scatter-add into updated ----------
__global__ __launch_bounds__(256) void ln_scatter(float* __restrict__ y,
                                                  const float* __restrict__ gamma,
                                                  const float* __restrict__ beta,
                                                  const int* __restrict__ s_i,
                                                  float* __restrict__ upd) {
    const int lane = threadIdx.x & 63;
    const long row = (long)blockIdx.x * 4 + (threadIdx.x >> 6);
    const long base = row * 768;
    float v[12];
#pragma unroll
    for (int i = 0; i < 12; ++i) v[i] = y[base + i * 64 + lane];
    float s = 0.f, q = 0.f;
#pragma unroll
    for (int i = 0; i < 12; ++i) { s += v[i]; q += v[i] * v[i]; }
#pragma unroll
    for (int off = 32; off > 0; off >>= 1) {
        s += __shfl_xor(s, off, 64);
        q += __shfl_xor(q, off, 64);
    }
    const float mu = s * (1.f / 768.f);
    const float var = q * (1.f / 768.f) - mu * mu;
    const float inv = rsqrtf(var + 1e-5f);
    const long si = s_i[row];
#pragma unroll
    for (int i = 0; i < 12; ++i) {
        int c = i * 64 + lane;
        float r = (v[i] - mu) * inv * gamma[c] + beta[c];
        y[base + c] = r;
        atomicAdd(&upd[si * 768 + c], r);
    }
}

// ---------- plain float4 copy ----------
__global__ void copy4(const float4* __restrict__ s, float4* __restrict__ d, long n) {
    long i = (long)blockIdx.x * blockDim.x + threadIdx.x;
    long stride = (long)gridDim.x * blockDim.x;
    for (; i < n; i += stride) d[i] = s[i];
}

extern "C" void kernel_launch(void* const* d_in, const int* in_sizes, int n_in,
                              void* d_out, int out_size, void* d_ws, size_t ws_size,
                              hipStream_t stream) {
    const float* u_t = (const float*)d_in[0];
    const int* s_i = (const int*)d_in[1];
    const float* emb = (const float*)d_in[2];
    const float* W1 = (const float*)d_in[3];
    const float* b1 = (const float*)d_in[4];
    const float* W2 = (const float*)d_in[5];
    const float* b2 = (const float*)d_in[6];
    const float* gamma = (const float*)d_in[7];
    const float* beta = (const float*)d_in[8];

    float* out = (float*)d_out;
    float* newh = out;             // [65536,768] f32 (y, then LN in place) - NOT in upd
    float* upd = out + 50331648L;  // [262144,768] f32 (scratch first, final last)

    // scratch inside upd (all dead before copy4 runs):
    u16* base = (u16*)upd;
    u16* xb = base;                    // [65536,1536] bf16
    u16* w1b = base + 100663296L;      // [2048,1536] bf16
    u16* hbuf = base + 103809024L;     // [65536,2048] bf16
    u16* w2b = base + 238026752L;      // [768,2048] bf16

    cvtbf<<<1024, 256, 0, stream>>>((const float4*)W1, (uint2*)w1b, 786432);
    cvtbf<<<1024, 256, 0, stream>>>((const float4*)W2, (uint2*)w2b, 393216);
    xbuild<<<49152, 256, 0, stream>>>(u_t, emb, s_i, xb);
    // GEMM1: M=65536, N=2048, K=1536 -> 2048 tiles (tanh-GELU, bf16 out)
    gemm256<1536, 24, 8, 0><<<2048, 512, 0, stream>>>(xb, w1b, b1, hbuf, nullptr);
    // GEMM2: M=65536, N=768, K=2048 -> 768 tiles (bias, f32 into newh)
    gemm256<2048, 32, 3, 1><<<768, 512, 0, stream>>>(hbuf, w2b, b2, nullptr, newh);
    copy4<<<2048, 256, 0, stream>>>((const float4*)emb, (float4*)upd, 50331648L);
    ln_scatter<<<16384, 256, 0, stream>>>(newh, gamma, beta, s_i, upd);
}

// Round 13
// 1353.394 us; speedup vs baseline: 1.0913x; 1.0785x over previous
//
#include <hip/hip_runtime.h>
#include <hip/hip_bf16.h>

typedef unsigned short u16;
typedef unsigned int u32;
typedef short bf16x8 __attribute__((ext_vector_type(8)));
typedef float f32x16 __attribute__((ext_vector_type(16)));

#define BAR() asm volatile("s_barrier" ::: "memory")
#define WAITV4() asm volatile("s_waitcnt vmcnt(4)" ::: "memory")
#define WAITV0() asm volatile("s_waitcnt vmcnt(0)" ::: "memory")
#define WAITL() asm volatile("s_waitcnt lgkmcnt(0)" ::: "memory")

// ---------- helpers ----------
__device__ __forceinline__ unsigned pk2(float lo, float hi) {
    unsigned a = (unsigned)__builtin_bit_cast(u16, __float2bfloat16(lo));
    unsigned b = (unsigned)__builtin_bit_cast(u16, __float2bfloat16(hi));
    return a | (b << 16);
}
__device__ __forceinline__ u16 f2bf(float v) {
    return __builtin_bit_cast(u16, __float2bfloat16(v));
}
__device__ __forceinline__ void gl_lds16(const u16* g, u16* l) {
    __builtin_amdgcn_global_load_lds(
        (const __attribute__((address_space(1))) u32*)g,
        (__attribute__((address_space(3))) u32*)l, 16, 0, 0);
}

// ---------- f32 -> bf16 weight convert ----------
__global__ void cvtbf(const float4* __restrict__ s, uint2* __restrict__ d, int n4) {
    int i = blockIdx.x * blockDim.x + threadIdx.x;
    int stride = gridDim.x * blockDim.x;
    for (; i < n4; i += stride) {
        float4 f = s[i];
        uint2 o;
        o.x = pk2(f.x, f.y);
        o.y = pk2(f.z, f.w);
        d[i] = o;
    }
}

// ---------- build x = [u_t | emb[s_i]] as bf16 [65536][1536] ----------
__global__ __launch_bounds__(256) void xbuild(const float* __restrict__ u_t,
                                              const float* __restrict__ emb,
                                              const int* __restrict__ s_i,
                                              u16* __restrict__ xb) {
    const long u = (long)blockIdx.x * blockDim.x + threadIdx.x;
    const int row = (int)(u / 192);
    const int c8 = (int)(u % 192);
    const float* src = (c8 < 96) ? (u_t + (long)row * 768 + c8 * 8)
                                 : (emb + (long)s_i[row] * 768 + (c8 - 96) * 8);
    float4 f0 = ((const float4*)src)[0];
    float4 f1 = ((const float4*)src)[1];
    uint4 o;
    o.x = pk2(f0.x, f0.y);
    o.y = pk2(f0.z, f0.w);
    o.z = pk2(f1.x, f1.y);
    o.w = pk2(f1.z, f1.w);
    *(uint4*)(xb + u * 8) = o;
}

// ---------- 256x256 8-phase GEMM (R8 skeleton), 32x32x16 MFMA --------------
// A [M][LDK] bf16, B [TN*256][LDK] bf16. EPI 0: tanh-GELU->bf16, EPI 1: bias->f32.
// Staging/vmcnt/barrier cadence identical to R8 (verified best). MFMA shape
// swapped 16x16x32 -> 32x32x16: half the instructions, same FLOPs/bytes.
// Operand layout: row/col = lane&31, k = (lane>>5)*8+e. C/D: col=lane&31,
// row=(reg&3)+8*(reg>>2)+4*(lane>>5) [m74/m101 verified].
// LDS: lds[buf][A/B][ks][256*32 u16], chunk swizzle c' = c ^ ((row>>1)&3),
// on global source + ds_read side (linear gl_lds dest, rule 21).
template <int LDK, int NT, int TN, int EPI>
__global__ __launch_bounds__(512, 2) void gemm256(
    const u16* __restrict__ Ag, const u16* __restrict__ Bg,
    const float* __restrict__ bias, u16* __restrict__ outb,
    float* __restrict__ outf) {
    __shared__ __align__(16) u16 lds[65536];  // 128 KiB

    const int tid = threadIdx.x;
    const int lane = tid & 63;
    const int wv = tid >> 6;
    const int wm = wv >> 2;  // 0..1
    const int wn = wv & 3;   // 0..3

    const int cpx = (int)gridDim.x >> 3;  // grid % 8 == 0
    const int tile = ((int)blockIdx.x & 7) * cpx + ((int)blockIdx.x >> 3);
    const int tm = tile / TN, tn = tile % TN;
    const long rowBase = (long)tm * 256;
    const long colBase = (long)tn * 256;

    // --- staging map: thread -> (row = tid>>2 [+128], swizzled 16B chunk) ---
    const int srow = tid >> 2;
    const int gch = (tid & 3) ^ ((tid >> 3) & 3);
    const u16* pA = Ag + (rowBase + srow) * (long)LDK + gch * 8;
    const u16* pB = Bg + (colBase + srow) * (long)LDK + gch * 8;
    const int dstBase = wv * 512;  // u16 units within 8KB sub-block

    auto stageA = [&](int kt, int ks, int b) {
        const u16* s = pA + kt * 64 + ks * 32;
        u16* d = lds + b * 32768 + ks * 8192 + dstBase;
        gl_lds16(s, d);
        gl_lds16(s + (long)128 * LDK, d + 4096);
    };
    auto stageB = [&](int kt, int ks, int b) {
        const u16* s = pB + kt * 64 + ks * 32;
        u16* d = lds + b * 32768 + 16384 + ks * 8192 + dstBase;
        gl_lds16(s, d);
        gl_lds16(s + (long)128 * LDK, d + 4096);
    };

    // --- fragment read offsets (u16 units, relative to 8KB ks-region) ---
    // 32x32x16 operand: row = base + frag*32 + (lane&31); k-chunk per k-step
    // s: chunk = s*2 + (lane>>5); swizzle ^((row>>1)&3).
    const int l31 = lane & 31, lk = lane >> 5;
    int offA[4][2], offB[2][2];
#pragma unroll
    for (int m = 0; m < 4; ++m) {
        int r = wm * 128 + m * 32 + l31;
#pragma unroll
        for (int s = 0; s < 2; ++s)
            offA[m][s] = r * 32 + (((s * 2 + lk) ^ ((r >> 1) & 3)) << 3);
    }
#pragma unroll
    for (int n = 0; n < 2; ++n) {
        int c = wn * 64 + n * 32 + l31;
#pragma unroll
        for (int s = 0; s < 2; ++s)
            offB[n][s] = c * 32 + (((s * 2 + lk) ^ ((c >> 1) & 3)) << 3);
    }

    f32x16 acc[4][2];
#pragma unroll
    for (int m = 0; m < 4; ++m)
#pragma unroll
        for (int n = 0; n < 2; ++n)
#pragma unroll
            for (int e = 0; e < 16; ++e) acc[m][n][e] = 0.f;

    // --- prologue: stage tile 0 fully; drain ks0 pair (ks1 in flight) ---
    stageA(0, 0, 0);
    stageB(0, 0, 0);
    stageA(0, 1, 0);
    stageB(0, 1, 0);
    WAITV4();
    BAR();

    bf16x8 bA[2][2], bB[2][2];
    for (int kt = 0; kt < NT; ++kt) {
        const int b = kt & 1;
        const u16* rA0 = lds + b * 32768;
        const u16* rB0 = rA0 + 16384;
        const u16* rA1 = rA0 + 8192;
        const u16* rB1 = rB0 + 8192;
        const bool pf = (kt + 1 < NT);

        // ---- P0: ks0, m-half0 (reads B ks0 too) ----
#pragma unroll
        for (int n = 0; n < 2; ++n)
#pragma unroll
            for (int s = 0; s < 2; ++s) bB[n][s] = *(const bf16x8*)(rB0 + offB[n][s]);
#pragma unroll
        for (int m = 0; m < 2; ++m)
#pragma unroll
            for (int s = 0; s < 2; ++s) bA[m][s] = *(const bf16x8*)(rA0 + offA[m][s]);
        if (pf) stageA(kt + 1, 0, b ^ 1);
        BAR();
        WAITL();
        __builtin_amdgcn_s_setprio(1);
#pragma unroll
        for (int m = 0; m < 2; ++m)
#pragma unroll
            for (int n = 0; n < 2; ++n)
#pragma unroll
                for (int s = 0; s < 2; ++s)
                    acc[m][n] = __builtin_amdgcn_mfma_f32_32x32x16_bf16(bA[m][s], bB[n][s], acc[m][n], 0, 0, 0);
        __builtin_amdgcn_s_setprio(0);
        BAR();

        // ---- P1: ks0, m-half1 ----
#pragma unroll
        for (int m = 0; m < 2; ++m)
#pragma unroll
            for (int s = 0; s < 2; ++s) bA[m][s] = *(const bf16x8*)(rA0 + offA[2 + m][s]);
        if (pf) stageB(kt + 1, 0, b ^ 1);
        BAR();
        WAITL();
        __builtin_amdgcn_s_setprio(1);
#pragma unroll
        for (int m = 0; m < 2; ++m)
#pragma unroll
            for (int n = 0; n < 2; ++n)
#pragma unroll
                for (int s = 0; s < 2; ++s)
                    acc[2 + m][n] = __builtin_amdgcn_mfma_f32_32x32x16_bf16(bA[m][s], bB[n][s], acc[2 + m][n], 0, 0, 0);
        __builtin_amdgcn_s_setprio(0);
        // tile t ks1 must land. Last tile: nothing newer -> drain (R3 lesson).
        if (pf) { WAITV4(); } else { WAITV0(); }
        BAR();

        // ---- P2: ks1, m-half0 (reads B ks1 too) ----
#pragma unroll
        for (int n = 0; n < 2; ++n)
#pragma unroll
            for (int s = 0; s < 2; ++s) bB[n][s] = *(const bf16x8*)(rB1 + offB[n][s]);
#pragma unroll
        for (int m = 0; m < 2; ++m)
#pragma unroll
            for (int s = 0; s < 2; ++s) bA[m][s] = *(const bf16x8*)(rA1 + offA[m][s]);
        if (pf) stageA(kt + 1, 1, b ^ 1);
        BAR();
        WAITL();
        __builtin_amdgcn_s_setprio(1);
#pragma unroll
        for (int m = 0; m < 2; ++m)
#pragma unroll
            for (int n = 0; n < 2; ++n)
#pragma unroll
                for (int s = 0; s < 2; ++s)
                    acc[m][n] = __builtin_amdgcn_mfma_f32_32x32x16_bf16(bA[m][s], bB[n][s], acc[m][n], 0, 0, 0);
        __builtin_amdgcn_s_setprio(0);
        BAR();

        // ---- P3: ks1, m-half1 ----
#pragma unroll
        for (int m = 0; m < 2; ++m)
#pragma unroll
            for (int s = 0; s < 2; ++s) bA[m][s] = *(const bf16x8*)(rA1 + offA[2 + m][s]);
        if (pf) stageB(kt + 1, 1, b ^ 1);
        BAR();
        WAITL();
        __builtin_amdgcn_s_setprio(1);
#pragma unroll
        for (int m = 0; m < 2; ++m)
#pragma unroll
            for (int n = 0; n < 2; ++n)
#pragma unroll
                for (int s = 0; s < 2; ++s)
                    acc[2 + m][n] = __builtin_amdgcn_mfma_f32_32x32x16_bf16(bA[m][s], bB[n][s], acc[2 + m][n], 0, 0, 0);
        __builtin_amdgcn_s_setprio(0);
        if (pf) { WAITV4(); } else { WAITV0(); }
        BAR();
    }

    // ---- epilogue: C/D 32x32 layout: col=lane&31, row=(r&3)+8*(r>>2)+4*lk --
    const int N = TN * 256;
#pragma unroll
    for (int n = 0; n < 2; ++n) {
        long gc = colBase + wn * 64 + n * 32 + l31;
        float bv = bias[gc];
#pragma unroll
        for (int m = 0; m < 4; ++m) {
            long rb = rowBase + wm * 128 + m * 32 + 4 * lk;
#pragma unroll
            for (int r = 0; r < 16; ++r) {
                long row = rb + (r & 3) + 8 * (r >> 2);
                float v = acc[m][n][r] + bv;
                if constexpr (EPI == 0) {
                    // gelu(v) = v * sigmoid(2u), u = 0.79788456(v + 0.044715 v^3)
                    float w = v * v;
                    float z = v * fmaf(w, -0.0713548162f, -1.5957691216f);  // -2u
                    v = __fdividef(v, 1.0f + __expf(z));
                    outb[row * N + gc] = f2bf(v);
                } else {
                    outf[row * N + gc] = v;
                }
            }
        }
    }
}

// ---------- LayerNorm (in place, f32) + scatter-add into updated ----------
__global__ __launch_bounds__(256) void ln_scatter(float* __restrict__ y,
                                                  const float* __restrict__ gamma,
                                                  const float* __restrict__ beta,
                                                  const int* __restrict__ s_i,
                                                  float* __restrict__ upd) {
    const int lane = threadIdx.x & 63;
    const long row = (long)blockIdx.x * 4 + (threadIdx.x >> 6);
    const long base = row * 768;
    float v[12];
#pragma unroll
    for (int i = 0; i < 12; ++i) v[i] = y[base + i * 64 + lane];
    float s = 0.f, q = 0.f;
#pragma unroll
    for (int i = 0; i < 12; ++i) { s += v[i]; q += v[i] * v[i]; }
#pragma unroll
    for (int off = 32; off > 0; off >>= 1) {
        s += __shfl_xor(s, off, 64);
        q += __shfl_xor(q, off, 64);
    }
    const float mu = s * (1.f / 768.f);
    const float var = q * (1.f / 768.f) - mu * mu;
    const float inv = rsqrtf(var + 1e-5f);
    const long si = s_i[row];
#pragma unroll
    for (int i = 0; i < 12; ++i) {
        int c = i * 64 + lane;
        float r = (v[i] - mu) * inv * gamma[c] + beta[c];
        y[base + c] = r;
        atomicAdd(&upd[si * 768 + c], r);
    }
}

// ---------- plain float4 copy ----------
__global__ void copy4(const float4* __restrict__ s, float4* __restrict__ d, long n) {
    long i = (long)blockIdx.x * blockDim.x + threadIdx.x;
    long stride = (long)gridDim.x * blockDim.x;
    for (; i < n; i += stride) d[i] = s[i];
}

extern "C" void kernel_launch(void* const* d_in, const int* in_sizes, int n_in,
                              void* d_out, int out_size, void* d_ws, size_t ws_size,
                              hipStream_t stream) {
    const float* u_t = (const float*)d_in[0];
    const int* s_i = (const int*)d_in[1];
    const float* emb = (const float*)d_in[2];
    const float* W1 = (const float*)d_in[3];
    const float* b1 = (const float*)d_in[4];
    const float* W2 = (const float*)d_in[5];
    const float* b2 = (const float*)d_in[6];
    const float* gamma = (const float*)d_in[7];
    const float* beta = (const float*)d_in[8];

    float* out = (float*)d_out;
    float* newh = out;             // [65536,768] f32 (y, then LN in place) - NOT in upd
    float* upd = out + 50331648L;  // [262144,768] f32 (scratch first, final last)

    // scratch inside upd (all dead before copy4 runs):
    u16* base = (u16*)upd;
    u16* xb = base;                    // [65536,1536] bf16
    u16* w1b = base + 100663296L;      // [2048,1536] bf16
    u16* hbuf = base + 103809024L;     // [65536,2048] bf16
    u16* w2b = base + 238026752L;      // [768,2048] bf16

    cvtbf<<<1024, 256, 0, stream>>>((const float4*)W1, (uint2*)w1b, 786432);
    cvtbf<<<1024, 256, 0, stream>>>((const float4*)W2, (uint2*)w2b, 393216);
    xbuild<<<49152, 256, 0, stream>>>(u_t, emb, s_i, xb);
    // GEMM1: M=65536, N=2048, K=1536 -> 2048 tiles (tanh-GELU, bf16 out)
    gemm256<1536, 24, 8, 0><<<2048, 512, 0, stream>>>(xb, w1b, b1, hbuf, nullptr);
    // GEMM2: M=65536, N=768, K=2048 -> 768 tiles (bias, f32 into newh)
    gemm256<2048, 32, 3, 1><<<768, 512, 0, stream>>>(hbuf, w2b, b2, nullptr, newh);
    copy4<<<2048, 256, 0, stream>>>((const float4*)emb, (float4*)upd, 50331648L);
    ln_scatter<<<16384, 256, 0, stream>>>(newh, gamma, beta, s_i, upd);
}

// Round 14
// 1326.631 us; speedup vs baseline: 1.1133x; 1.0202x over previous
//
#include <hip/hip_runtime.h>
#include <hip/hip_bf16.h>

typedef unsigned short u16;
typedef unsigned int u32;
typedef short bf16x8 __attribute__((ext_vector_type(8)));
typedef float f32x4 __attribute__((ext_vector_type(4)));

#define BAR() asm volatile("s_barrier" ::: "memory")
#define WAITV4() asm volatile("s_waitcnt vmcnt(4)" ::: "memory")
#define WAITV0() asm volatile("s_waitcnt vmcnt(0)" ::: "memory")
#define WAITL() asm volatile("s_waitcnt lgkmcnt(0)" ::: "memory")

// ---------- helpers ----------
__device__ __forceinline__ unsigned pk2(float lo, float hi) {
    unsigned a = (unsigned)__builtin_bit_cast(u16, __float2bfloat16(lo));
    unsigned b = (unsigned)__builtin_bit_cast(u16, __float2bfloat16(hi));
    return a | (b << 16);
}
__device__ __forceinline__ u16 f2bf(float v) {
    return __builtin_bit_cast(u16, __float2bfloat16(v));
}
__device__ __forceinline__ void gl_lds16(const u16* g, u16* l) {
    __builtin_amdgcn_global_load_lds(
        (const __attribute__((address_space(1))) u32*)g,
        (__attribute__((address_space(3))) u32*)l, 16, 0, 0);
}

// ---------- f32 -> bf16 weight convert ----------
__global__ void cvtbf(const float4* __restrict__ s, uint2* __restrict__ d, int n4) {
    int i = blockIdx.x * blockDim.x + threadIdx.x;
    int stride = gridDim.x * blockDim.x;
    for (; i < n4; i += stride) {
        float4 f = s[i];
        uint2 o;
        o.x = pk2(f.x, f.y);
        o.y = pk2(f.z, f.w);
        d[i] = o;
    }
}

// ---------- build x = [u_t | emb[s_i]] as bf16 [65536][1536] ----------
__global__ __launch_bounds__(256) void xbuild(const float* __restrict__ u_t,
                                              const float* __restrict__ emb,
                                              const int* __restrict__ s_i,
                                              u16* __restrict__ xb) {
    const long u = (long)blockIdx.x * blockDim.x + threadIdx.x;
    const int row = (int)(u / 192);
    const int c8 = (int)(u % 192);
    const float* src = (c8 < 96) ? (u_t + (long)row * 768 + c8 * 8)
                                 : (emb + (long)s_i[row] * 768 + (c8 - 96) * 8);
    float4 f0 = ((const float4*)src)[0];
    float4 f1 = ((const float4*)src)[1];
    uint4 o;
    o.x = pk2(f0.x, f0.y);
    o.y = pk2(f0.z, f0.w);
    o.z = pk2(f1.x, f1.y);
    o.w = pk2(f1.z, f1.w);
    *(uint4*)(xb + u * 8) = o;
}

// ---------- 256x256 GEMM, m201-faithful: 8 phases / 2 K-tiles --------------
// A [M][LDK] bf16, B [TN*256][LDK] bf16. EPI 0: tanh-GELU->bf16, EPI 1: bias->f32.
// One half-tile (2 gl_lds) staged per phase; counted vmcnt(4) ONLY at
// phases 4 and 8 (once per K-tile); sub-buffer slot recycling: a ks-half is
// restaged as soon as its readers (2 phases) are done. Buffers fixed:
// buf0 = even K-tile, buf1 = odd. Tail drains vmcnt(0) (R3 lesson).
// Stage stream per iter tp (pair j): ph0 A(2tp+1,ks1)->b1, ph1 B(2tp+1,ks1)->b1,
// ph2 A(2tp+2,ks0)->b0, ph3 B(..)->b0, ph4 A(2tp+2,ks1)->b0, ph5 B(..)->b0,
// ph6 A(2tp+3,ks0)->b1, ph7 B(..)->b1.  NT must be even.
// LDS: lds[buf][A/B][ks][256*32 u16], chunk swizzle c' = c ^ ((row>>1)&3),
// on global source + ds_read side (linear gl_lds dest, rule 21).
template <int LDK, int NT, int TN, int EPI>
__global__ __launch_bounds__(512, 2) void gemm256(
    const u16* __restrict__ Ag, const u16* __restrict__ Bg,
    const float* __restrict__ bias, u16* __restrict__ outb,
    float* __restrict__ outf) {
    __shared__ __align__(16) u16 lds[65536];  // 128 KiB

    const int tid = threadIdx.x;
    const int lane = tid & 63;
    const int wv = tid >> 6;
    const int wm = wv >> 2;  // 0..1
    const int wn = wv & 3;   // 0..3

    const int cpx = (int)gridDim.x >> 3;  // grid % 8 == 0
    const int tile = ((int)blockIdx.x & 7) * cpx + ((int)blockIdx.x >> 3);
    const int tm = tile / TN, tn = tile % TN;
    const long rowBase = (long)tm * 256;
    const long colBase = (long)tn * 256;

    // --- staging map: thread -> (row = tid>>2 [+128], swizzled 16B chunk) ---
    const int srow = tid >> 2;
    const int gch = (tid & 3) ^ ((tid >> 3) & 3);
    const u16* pA = Ag + (rowBase + srow) * (long)LDK + gch * 8;
    const u16* pB = Bg + (colBase + srow) * (long)LDK + gch * 8;
    const int dstBase = wv * 512;  // u16 units within 8KB sub-block

    auto stageA = [&](int kt, int ks, int b) {
        const u16* s = pA + kt * 64 + ks * 32;
        u16* d = lds + b * 32768 + ks * 8192 + dstBase;
        gl_lds16(s, d);
        gl_lds16(s + (long)128 * LDK, d + 4096);
    };
    auto stageB = [&](int kt, int ks, int b) {
        const u16* s = pB + kt * 64 + ks * 32;
        u16* d = lds + b * 32768 + 16384 + ks * 8192 + dstBase;
        gl_lds16(s, d);
        gl_lds16(s + (long)128 * LDK, d + 4096);
    };

    // --- fragment read offsets (u16 units, relative to 8KB ks-region) ---
    const int l15 = lane & 15, lc = lane >> 4;
    int offA[8], offB[4];
#pragma unroll
    for (int i = 0; i < 8; ++i) {
        int r = wm * 128 + i * 16 + l15;
        offA[i] = r * 32 + ((lc ^ ((r >> 1) & 3)) << 3);
    }
#pragma unroll
    for (int n = 0; n < 4; ++n) {
        int r = wn * 64 + n * 16 + l15;
        offB[n] = r * 32 + ((lc ^ ((r >> 1) & 3)) << 3);
    }

    f32x4 acc[8][4];
    const f32x4 zero = {0.f, 0.f, 0.f, 0.f};
#pragma unroll
    for (int m = 0; m < 8; ++m)
#pragma unroll
        for (int n = 0; n < 4; ++n) acc[m][n] = zero;

    // --- prologue: stage b0 (tile 0, both ks) + b1.ks0 (tile 1) = 12 loads;
    //     drain the 8 tile-0 loads (keep tile-1 ks0 pair in flight) ---
    stageA(0, 0, 0);
    stageB(0, 0, 0);
    stageA(0, 1, 0);
    stageB(0, 1, 0);
    stageA(1, 0, 1);
    stageB(1, 0, 1);
    WAITV4();
    BAR();

    const u16* rA0k0 = lds;
    const u16* rA0k1 = lds + 8192;
    const u16* rB0k0 = lds + 16384;
    const u16* rB0k1 = lds + 24576;
    const u16* rA1k0 = lds + 32768;
    const u16* rA1k1 = lds + 40960;
    const u16* rB1k0 = lds + 49152;
    const u16* rB1k1 = lds + 57344;

    bf16x8 bA[4], bB[4];
    const int NT2 = NT / 2;
    for (int tp = 0; tp < NT2; ++tp) {
        const int t1 = 2 * tp + 1;
        const int t2 = 2 * tp + 2;
        const bool pf = (t2 < NT);

        // ---- PH0: b0.ks0, mh0 ----
#pragma unroll
        for (int n = 0; n < 4; ++n) bB[n] = *(const bf16x8*)(rB0k0 + offB[n]);
#pragma unroll
        for (int m = 0; m < 4; ++m) bA[m] = *(const bf16x8*)(rA0k0 + offA[m]);
        stageA(t1, 1, 1);  // H6: b1.A.ks1 (slot freed ph6-7 of prev iter)
        BAR();
        WAITL();
        __builtin_amdgcn_s_setprio(1);
#pragma unroll
        for (int m = 0; m < 4; ++m)
#pragma unroll
            for (int n = 0; n < 4; ++n)
                acc[m][n] = __builtin_amdgcn_mfma_f32_16x16x32_bf16(bA[m], bB[n], acc[m][n], 0, 0, 0);
        __builtin_amdgcn_s_setprio(0);
        BAR();

        // ---- PH1: b0.ks0, mh1 ----
#pragma unroll
        for (int m = 0; m < 4; ++m) bA[m] = *(const bf16x8*)(rA0k0 + offA[4 + m]);
        stageB(t1, 1, 1);  // H7
        BAR();
        WAITL();
        __builtin_amdgcn_s_setprio(1);
#pragma unroll
        for (int m = 0; m < 4; ++m)
#pragma unroll
            for (int n = 0; n < 4; ++n)
                acc[4 + m][n] = __builtin_amdgcn_mfma_f32_16x16x32_bf16(bA[m], bB[n], acc[4 + m][n], 0, 0, 0);
        __builtin_amdgcn_s_setprio(0);
        BAR();

        // ---- PH2: b0.ks1, mh0 ----
#pragma unroll
        for (int n = 0; n < 4; ++n) bB[n] = *(const bf16x8*)(rB0k1 + offB[n]);
#pragma unroll
        for (int m = 0; m < 4; ++m) bA[m] = *(const bf16x8*)(rA0k1 + offA[m]);
        if (pf) stageA(t2, 0, 0);  // H0': b0.A.ks0 (freed after ph1)
        BAR();
        WAITL();
        __builtin_amdgcn_s_setprio(1);
#pragma unroll
        for (int m = 0; m < 4; ++m)
#pragma unroll
            for (int n = 0; n < 4; ++n)
                acc[m][n] = __builtin_amdgcn_mfma_f32_16x16x32_bf16(bA[m], bB[n], acc[m][n], 0, 0, 0);
        __builtin_amdgcn_s_setprio(0);
        BAR();

        // ---- PH3: b0.ks1, mh1 ----
#pragma unroll
        for (int m = 0; m < 4; ++m) bA[m] = *(const bf16x8*)(rA0k1 + offA[4 + m]);
        if (pf) stageB(t2, 0, 0);  // H1'
        BAR();
        WAITL();
        __builtin_amdgcn_s_setprio(1);
#pragma unroll
        for (int m = 0; m < 4; ++m)
#pragma unroll
            for (int n = 0; n < 4; ++n)
                acc[4 + m][n] = __builtin_amdgcn_mfma_f32_16x16x32_bf16(bA[m], bB[n], acc[4 + m][n], 0, 0, 0);
        __builtin_amdgcn_s_setprio(0);
        // K-tile boundary wait #1: keep 2 newest half-tiles (H0',H1');
        // guarantees b1's four halves (H4@ph6 prev, H5@ph7 prev, H6@ph0,
        // H7@ph1) all landed. Tail: drain everything (R3 lesson).
        if (pf) { WAITV4(); } else { WAITV0(); }
        BAR();

        // ---- PH4: b1.ks0, mh0 ----
#pragma unroll
        for (int n = 0; n < 4; ++n) bB[n] = *(const bf16x8*)(rB1k0 + offB[n]);
#pragma unroll
        for (int m = 0; m < 4; ++m) bA[m] = *(const bf16x8*)(rA1k0 + offA[m]);
        if (pf) stageA(t2, 1, 0);  // H2': b0.A.ks1 (freed after ph3)
        BAR();
        WAITL();
        __builtin_amdgcn_s_setprio(1);
#pragma unroll
        for (int m = 0; m < 4; ++m)
#pragma unroll
            for (int n = 0; n < 4; ++n)
                acc[m][n] = __builtin_amdgcn_mfma_f32_16x16x32_bf16(bA[m], bB[n], acc[m][n], 0, 0, 0);
        __builtin_amdgcn_s_setprio(0);
        BAR();

        // ---- PH5: b1.ks0, mh1 ----
#pragma unroll
        for (int m = 0; m < 4; ++m) bA[m] = *(const bf16x8*)(rA1k0 + offA[4 + m]);
        if (pf) stageB(t2, 1, 0);  // H3'
        BAR();
        WAITL();
        __builtin_amdgcn_s_setprio(1);
#pragma unroll
        for (int m = 0; m < 4; ++m)
#pragma unroll
            for (int n = 0; n < 4; ++n)
                acc[4 + m][n] = __builtin_amdgcn_mfma_f32_16x16x32_bf16(bA[m], bB[n], acc[4 + m][n], 0, 0, 0);
        __builtin_amdgcn_s_setprio(0);
        BAR();

        // ---- PH6: b1.ks1, mh0 ----
#pragma unroll
        for (int n = 0; n < 4; ++n) bB[n] = *(const bf16x8*)(rB1k1 + offB[n]);
#pragma unroll
        for (int m = 0; m < 4; ++m) bA[m] = *(const bf16x8*)(rA1k1 + offA[m]);
        if (pf) stageA(t2 + 1, 0, 1);  // H4': b1.A.ks0 (freed after ph5)
        BAR();
        WAITL();
        __builtin_amdgcn_s_setprio(1);
#pragma unroll
        for (int m = 0; m < 4; ++m)
#pragma unroll
            for (int n = 0; n < 4; ++n)
                acc[m][n] = __builtin_amdgcn_mfma_f32_16x16x32_bf16(bA[m], bB[n], acc[m][n], 0, 0, 0);
        __builtin_amdgcn_s_setprio(0);
        BAR();

        // ---- PH7: b1.ks1, mh1 ----
#pragma unroll
        for (int m = 0; m < 4; ++m) bA[m] = *(const bf16x8*)(rA1k1 + offA[4 + m]);
        if (pf) stageB(t2 + 1, 0, 1);  // H5'
        BAR();
        WAITL();
        __builtin_amdgcn_s_setprio(1);
#pragma unroll
        for (int m = 0; m < 4; ++m)
#pragma unroll
            for (int n = 0; n < 4; ++n)
                acc[4 + m][n] = __builtin_amdgcn_mfma_f32_16x16x32_bf16(bA[m], bB[n], acc[4 + m][n], 0, 0, 0);
        __builtin_amdgcn_s_setprio(0);
        // K-tile boundary wait #2: keep 2 newest (H4',H5'); guarantees next
        // pair's b0 halves (H0'..H3') landed for ph0-3 of next iter.
        if (pf) { WAITV4(); } else { WAITV0(); }
        BAR();
    }

    // ---- epilogue ----
    const int N = TN * 256;
#pragma unroll
    for (int n = 0; n < 4; ++n) {
        long gc = colBase + wn * 64 + n * 16 + l15;
        float bv = bias[gc];
#pragma unroll
        for (int i = 0; i < 8; ++i) {
            long gr = rowBase + wm * 128 + i * 16 + (lc << 2);
#pragma unroll
            for (int j = 0; j < 4; ++j) {
                float v = acc[i][n][j] + bv;
                if constexpr (EPI == 0) {
                    // gelu(v) = v * sigmoid(2u), u = 0.79788456(v + 0.044715 v^3)
                    float w = v * v;
                    float z = v * fmaf(w, -0.0713548162f, -1.5957691216f);  // -2u
                    v = __fdividef(v, 1.0f + __expf(z));
                    outb[(gr + j) * N + gc] = f2bf(v);
                } else {
                    outf[(gr + j) * N + gc] = v;
                }
            }
        }
    }
}

// ---------- LayerNorm (in place, f32) + scatter-add into updated ----------
__global__ __launch_bounds__(256) void ln_scatter(float* __restrict__ y,
                                                  const float* __restrict__ gamma,
                                                  const float* __restrict__ beta,
                                                  const int* __restrict__ s_i,
                                                  float* __restrict__ upd) {
    const int lane = threadIdx.x & 63;
    const long row = (long)blockIdx.x * 4 + (threadIdx.x >> 6);
    const long base = row * 768;
    float v[12];
#pragma unroll
    for (int i = 0; i < 12; ++i) v[i] = y[base + i * 64 + lane];
    float s = 0.f, q = 0.f;
#pragma unroll
    for (int i = 0; i < 12; ++i) { s += v[i]; q += v[i] * v[i]; }
#pragma unroll
    for (int off = 32; off > 0; off >>= 1) {
        s += __shfl_xor(s, off, 64);
        q += __shfl_xor(q, off, 64);
    }
    const float mu = s * (1.f / 768.f);
    const float var = q * (1.f / 768.f) - mu * mu;
    const float inv = rsqrtf(var + 1e-5f);
    const long si = s_i[row];
#pragma unroll
    for (int i = 0; i < 12; ++i) {
        int c = i * 64 + lane;
        float r = (v[i] - mu) * inv * gamma[c] + beta[c];
        y[base + c] = r;
        atomicAdd(&upd[si * 768 + c], r);
    }
}

// ---------- plain float4 copy ----------
__global__ void copy4(const float4* __restrict__ s, float4* __restrict__ d, long n) {
    long i = (long)blockIdx.x * blockDim.x + threadIdx.x;
    long stride = (long)gridDim.x * blockDim.x;
    for (; i < n; i += stride) d[i] = s[i];
}

extern "C" void kernel_launch(void* const* d_in, const int* in_sizes, int n_in,
                              void* d_out, int out_size, void* d_ws, size_t ws_size,
                              hipStream_t stream) {
    const float* u_t = (const float*)d_in[0];
    const int* s_i = (const int*)d_in[1];
    const float* emb = (const float*)d_in[2];
    const float* W1 = (const float*)d_in[3];
    const float* b1 = (const float*)d_in[4];
    const float* W2 = (const float*)d_in[5];
    const float* b2 = (const float*)d_in[6];
    const float* gamma = (const float*)d_in[7];
    const float* beta = (const float*)d_in[8];

    float* out = (float*)d_out;
    float* newh = out;             // [65536,768] f32 (y, then LN in place) - NOT in upd
    float* upd = out + 50331648L;  // [262144,768] f32 (scratch first, final last)

    // scratch inside upd (all dead before copy4 runs):
    u16* base = (u16*)upd;
    u16* xb = base;                    // [65536,1536] bf16
    u16* w1b = base + 100663296L;      // [2048,1536] bf16
    u16* hbuf = base + 103809024L;     // [65536,2048] bf16
    u16* w2b = base + 238026752L;      // [768,2048] bf16

    cvtbf<<<1024, 256, 0, stream>>>((const float4*)W1, (uint2*)w1b, 786432);
    cvtbf<<<1024, 256, 0, stream>>>((const float4*)W2, (uint2*)w2b, 393216);
    xbuild<<<49152, 256, 0, stream>>>(u_t, emb, s_i, xb);
    // GEMM1: M=65536, N=2048, K=1536 -> 2048 tiles (tanh-GELU, bf16 out)
    gemm256<1536, 24, 8, 0><<<2048, 512, 0, stream>>>(xb, w1b, b1, hbuf, nullptr);
    // GEMM2: M=65536, N=768, K=2048 -> 768 tiles (bias, f32 into newh)
    gemm256<2048, 32, 3, 1><<<768, 512, 0, stream>>>(hbuf, w2b, b2, nullptr, newh);
    copy4<<<2048, 256, 0, stream>>>((const float4*)emb, (float4*)upd, 50331648L);
    ln_scatter<<<16384, 256, 0, stream>>>(newh, gamma, beta, s_i, upd);
}